// Round 16
// baseline (105.038 us; speedup 1.0000x reference)
//
#include <hip/hip_runtime.h>

#define NB   4
#define CIN  32
#define HH   56
#define WW   56
#define GOUT 8
#define LOUT 8
#define KK   9
#define HW   (HH * WW)        // 3136
#define WSLICE 2304           // GOUT-slice floats per c (8*9*4*8)
#define WS_G 292              // padded per-g LDS stride -> conflict-free b128 reads
#define XCOLS 58              // staged cols (w-1 .. w+1 halo)
#define XCH  36               // padded ch stride: 36 floats = 144 B (16B-aligned float4 slots)
#define XTOT (3 * XCOLS * CIN)   // 5568 staged elements
#define THREADS 448           // 56 pixels (one image row) x 8 g = 7 waves

typedef float v2f __attribute__((ext_vector_type(2)));
typedef float v4f __attribute__((ext_vector_type(4)));

static __device__ __forceinline__ v2f fma2(v2f a, v2f b, v2f c) {
    return __builtin_elementwise_fma(a, b, c);
}

// DPP xor-add over the 8-lane g-group: quad_perm(1,0,3,2)=0xB1 (lane^1),
// quad_perm(2,3,0,1)=0x4E (lane^2), row_half_mirror=0x141 (lane^7 within 8;
// valid for step 3 because quad-sums are already quad-uniform).
#define DPP_XADD(x, CTRL) \
    (x) += __int_as_float(__builtin_amdgcn_update_dpp( \
        0, __float_as_int(x), (CTRL), 0xF, 0xF, true))

__global__ __launch_bounds__(THREADS, 7) void caps_fused_kernel(
    const float* __restrict__ x, const float* __restrict__ wt,
    float* __restrict__ out)
{
    __shared__ float ws[8 * WS_G];                       // 9344 B
    __shared__ __align__(16) float xs[3 * XCOLS * XCH];  // 25056 B

    const int tid = threadIdx.x;
    const int c = blockIdx.y;
    const int rr = blockIdx.x;        // n*56 + h
    const int n = rr / HH;
    const int h = rr - n * HH;

    const int g = tid & 7;
    const int w = tid >> 3;           // 0..55

    // ---- stage x rows h-1..h+1 into xs[row][col][ch] (zero border) ----
    // i -> (seg = row*32+ch, col); consecutive i -> consecutive col -> coalesced
    const float* xn = x + (size_t)n * CIN * HW;
    for (int i = tid; i < XTOT; i += THREADS) {
        const int seg = i / XCOLS;
        const int col = i - seg * XCOLS;
        const int ch  = seg & 31;
        const int row = seg >> 5;
        const int hh  = h - 1 + row;
        const int wc  = col - 1;
        const bool ok = ((unsigned)hh < (unsigned)HH) && ((unsigned)wc < (unsigned)WW);
        xs[(row * XCOLS + col) * XCH + ch] = ok ? xn[ch * HW + hh * WW + wc] : 0.0f;
    }

    // ---- stage this c's weight slice: [g][k][l][m], per-g padded to 292 ----
    if (tid < 256) {
        const int gg = tid >> 5;
        const int r0 = tid & 31;
        const float* src = wt + c * WSLICE + gg * 288;
        float* dst = ws + gg * WS_G;
        #pragma unroll
        for (int j = 0; j < 9; ++j)
            dst[r0 + j * 32] = src[r0 + j * 32];
    }
    __syncthreads();

    // ---- x patch: 9 aligned b128 reads from LDS ----
    v4f xv4[KK];
    #pragma unroll
    for (int ki = 0; ki < 3; ++ki)
        #pragma unroll
        for (int kj = 0; kj < 3; ++kj)
            xv4[ki * 3 + kj] = *reinterpret_cast<const v4f*>(
                &xs[((ki * XCOLS) + (w + kj)) * XCH + g * 4]);

    // ---- priors (packed pairs): pr2[k][j] = m-pair j of prior vector k ----
    v2f pr2[KK][4];
    v2f ks2[4] = {v2f{0.f,0.f}, v2f{0.f,0.f}, v2f{0.f,0.f}, v2f{0.f,0.f}};

    const float* wg = &ws[g * WS_G];
    #pragma unroll
    for (int k = 0; k < KK; ++k) {
        v2f a0 = {0.f,0.f}, a1 = {0.f,0.f}, a2 = {0.f,0.f}, a3 = {0.f,0.f};
        #pragma unroll
        for (int l = 0; l < 4; ++l) {
            const float xsv = xv4[k][l];
            const v2f xs2 = {xsv, xsv};
            const v4f w01 = *reinterpret_cast<const v4f*>(wg + k * 32 + l * 8);
            const v4f w23 = *reinterpret_cast<const v4f*>(wg + k * 32 + l * 8 + 4);
            a0 = fma2(xs2, __builtin_shufflevector(w01, w01, 0, 1), a0);
            a1 = fma2(xs2, __builtin_shufflevector(w01, w01, 2, 3), a1);
            a2 = fma2(xs2, __builtin_shufflevector(w23, w23, 0, 1), a2);
            a3 = fma2(xs2, __builtin_shufflevector(w23, w23, 2, 3), a3);
        }
        pr2[k][0] = a0; pr2[k][1] = a1; pr2[k][2] = a2; pr2[k][3] = a3;
        ks2[0] += a0; ks2[1] += a1; ks2[2] += a2; ks2[3] += a3;
    }

    // ---- dynamic routing, ITERS = 3 (normalized probs — bounded) ----
    float logits[KK];
    #pragma unroll
    for (int k = 0; k < KK; ++k) logits[k] = 0.0f;

    v2f vv[4];
    #pragma unroll
    for (int it = 0; it < 3; ++it) {
        v2f s2[4];
        if (it == 0) {
            #pragma unroll
            for (int j = 0; j < 4; ++j) s2[j] = ks2[j] * (1.0f / 9.0f);
        } else {
            float e[KK];
            float sum = 0.0f;
            #pragma unroll
            for (int k = 0; k < KK; ++k) { e[k] = __expf(logits[k]); sum += e[k]; }
            const float inv = 1.0f / sum;
            #pragma unroll
            for (int j = 0; j < 4; ++j) s2[j] = v2f{0.f, 0.f};
            #pragma unroll
            for (int k = 0; k < KK; ++k) {
                const v2f ek = {e[k], e[k]};
                #pragma unroll
                for (int j = 0; j < 4; ++j) s2[j] = fma2(ek, pr2[k][j], s2[j]);
            }
            const v2f inv2 = {inv, inv};
            #pragma unroll
            for (int j = 0; j < 4; ++j) s2[j] *= inv2;
        }

        // g-group all-reduce via DPP (VALU-only, no LDS pipe)
        #pragma unroll
        for (int j = 0; j < 4; ++j) { DPP_XADD(s2[j].x, 0xB1); DPP_XADD(s2[j].y, 0xB1); }
        #pragma unroll
        for (int j = 0; j < 4; ++j) { DPP_XADD(s2[j].x, 0x4E); DPP_XADD(s2[j].y, 0x4E); }
        #pragma unroll
        for (int j = 0; j < 4; ++j) { DPP_XADD(s2[j].x, 0x141); DPP_XADD(s2[j].y, 0x141); }

        // squash: f = sqrt(n2)/(1+n2) via rsq+rcp — denominator >= 1, NaN-free
        v2f tq = s2[0] * s2[0];
        tq = fma2(s2[1], s2[1], tq);
        tq = fma2(s2[2], s2[2], tq);
        tq = fma2(s2[3], s2[3], tq);
        const float n2 = tq.x + tq.y;
        const float f = n2 * __builtin_amdgcn_rsqf(fmaxf(n2, 1e-30f))
                           * __builtin_amdgcn_rcpf(1.0f + n2);
        const v2f f2 = {f, f};
        #pragma unroll
        for (int j = 0; j < 4; ++j) vv[j] = f2 * s2[j];

        if (it != 2) {
            #pragma unroll
            for (int k = 0; k < KK; ++k) {
                v2f d2 = pr2[k][0] * vv[0];
                d2 = fma2(pr2[k][1], vv[1], d2);
                d2 = fma2(pr2[k][2], vv[2], d2);
                d2 = fma2(pr2[k][3], vv[3], d2);
                logits[k] += d2.x + d2.y;
            }
        }
    }

    // lane (w, g) writes output component m = g (static select chain)
    const float vs[8] = { vv[0].x, vv[0].y, vv[1].x, vv[1].y,
                          vv[2].x, vv[2].y, vv[3].x, vv[3].y };
    float outv = vs[0];
    #pragma unroll
    for (int m = 1; m < LOUT; ++m) if (g == m) outv = vs[m];
    out[(n * GOUT * LOUT + c * LOUT + g) * HW + h * WW + w] = outv;
}

extern "C" void kernel_launch(void* const* d_in, const int* in_sizes, int n_in,
                              void* d_out, int out_size, void* d_ws, size_t ws_size,
                              hipStream_t stream) {
    const float* x  = (const float*)d_in[0];
    const float* wt = (const float*)d_in[1];
    float* out = (float*)d_out;

    dim3 grid(NB * HH, GOUT);   // 224 x 8, 448 threads (one image row x one c)
    caps_fused_kernel<<<grid, dim3(THREADS), 0, stream>>>(x, wt, out);
}

// Round 17
// 31.559 us; speedup vs baseline: 3.3283x; 3.3283x over previous
//
#include <hip/hip_runtime.h>

#define NB   4
#define CIN  32
#define HH   56
#define WW   56
#define GOUT 8
#define LOUT 8
#define KK   9
#define HW   (HH * WW)        // 3136
#define WSLICE 2304           // GOUT-slice floats per c (8*9*4*8)
#define WS_G 292              // padded per-g LDS stride -> conflict-free b128 reads
#define XCOLS 58              // staged cols (w-1 .. w+1 halo)
#define XCH  36               // padded ch stride: 36 floats = 144 B (16B-aligned float4 slots)
#define NSLOT (3 * XCOLS * 8) // 1392 float4 staging slots (row, col, chBlk)
#define THREADS 448           // 56 pixels (one image row) x 8 g = 7 waves

typedef float v2f __attribute__((ext_vector_type(2)));
typedef float v4f __attribute__((ext_vector_type(4)));

static __device__ __forceinline__ v2f fma2(v2f a, v2f b, v2f c) {
    return __builtin_elementwise_fma(a, b, c);
}

// DPP xor-add over the 8-lane g-group: quad_perm(1,0,3,2)=0xB1 (lane^1),
// quad_perm(2,3,0,1)=0x4E (lane^2), row_half_mirror=0x141 (lane^7 within 8;
// valid for step 3 because quad-sums are already quad-uniform).
#define DPP_XADD(x, CTRL) \
    (x) += __int_as_float(__builtin_amdgcn_update_dpp( \
        0, __float_as_int(x), (CTRL), 0xF, 0xF, true))

// NOTE: 2nd launch-bounds arg divides the UNIFIED (VGPR+AGPR) file: 512/W.
// W=7 gave a 73-reg budget -> scratch catastrophe (r16). W=2 -> 256 regs.
__global__ __launch_bounds__(THREADS, 2) void caps_fused_kernel(
    const float* __restrict__ x, const float* __restrict__ wt,
    float* __restrict__ out)
{
    __shared__ __align__(16) float ws[8 * WS_G];         // 9344 B
    __shared__ __align__(16) float xs[3 * XCOLS * XCH];  // 25056 B

    const int tid = threadIdx.x;
    const int c = blockIdx.y;
    const int rr = blockIdx.x;        // n*56 + h
    const int n = rr / HH;
    const int h = rr - n * HH;

    const int g = tid & 7;
    const int w = tid >> 3;           // 0..55

    // ---- stage x rows h-1..h+1 into xs[row][col][ch] via float4 slots ----
    // slot i = (chBlk*3 + row)*58 + col: col fastest -> coalesced global reads,
    // b128 LDS writes -> optimally-tiled banks (no scalar 8-way conflicts)
    const float* xn = x + (size_t)n * CIN * HW;
    #pragma unroll
    for (int ii = 0; ii < 4; ++ii) {
        const int i = tid + ii * THREADS;
        if (i < NSLOT) {
            const int s   = i / XCOLS;        // chBlk*3 + row  (const-div -> magic mul)
            const int col = i - s * XCOLS;
            const int chB = s / 3;
            const int row = s - chB * 3;
            const int hh  = h - 1 + row;
            const int wc  = col - 1;
            const bool ok = ((unsigned)hh < (unsigned)HH) && ((unsigned)wc < (unsigned)WW);
            const float* src = xn + (chB * 4) * HW + hh * WW + wc;
            v4f val;
            val.x = ok ? src[0]      : 0.0f;
            val.y = ok ? src[HW]     : 0.0f;
            val.z = ok ? src[2 * HW] : 0.0f;
            val.w = ok ? src[3 * HW] : 0.0f;
            *reinterpret_cast<v4f*>(&xs[(row * XCOLS + col) * XCH + chB * 4]) = val;
        }
    }

    // ---- stage this c's weight slice: [g][k][l][m], per-g padded to 292 ----
    if (tid < 256) {
        const int gg = tid >> 5;
        const int r0 = tid & 31;
        const float* src = wt + c * WSLICE + gg * 288;
        float* dst = ws + gg * WS_G;
        #pragma unroll
        for (int j = 0; j < 9; ++j)
            dst[r0 + j * 32] = src[r0 + j * 32];
    }
    __syncthreads();

    // ---- x patch: 9 aligned b128 reads from LDS ----
    v4f xv4[KK];
    #pragma unroll
    for (int ki = 0; ki < 3; ++ki)
        #pragma unroll
        for (int kj = 0; kj < 3; ++kj)
            xv4[ki * 3 + kj] = *reinterpret_cast<const v4f*>(
                &xs[((ki * XCOLS) + (w + kj)) * XCH + g * 4]);

    // ---- priors (packed pairs): pr2[k][j] = m-pair j of prior vector k ----
    v2f pr2[KK][4];
    v2f ks2[4] = {v2f{0.f,0.f}, v2f{0.f,0.f}, v2f{0.f,0.f}, v2f{0.f,0.f}};

    const float* wg = &ws[g * WS_G];
    #pragma unroll
    for (int k = 0; k < KK; ++k) {
        v2f a0 = {0.f,0.f}, a1 = {0.f,0.f}, a2 = {0.f,0.f}, a3 = {0.f,0.f};
        #pragma unroll
        for (int l = 0; l < 4; ++l) {
            const float xsv = xv4[k][l];
            const v2f xs2 = {xsv, xsv};
            const v4f w01 = *reinterpret_cast<const v4f*>(wg + k * 32 + l * 8);
            const v4f w23 = *reinterpret_cast<const v4f*>(wg + k * 32 + l * 8 + 4);
            a0 = fma2(xs2, __builtin_shufflevector(w01, w01, 0, 1), a0);
            a1 = fma2(xs2, __builtin_shufflevector(w01, w01, 2, 3), a1);
            a2 = fma2(xs2, __builtin_shufflevector(w23, w23, 0, 1), a2);
            a3 = fma2(xs2, __builtin_shufflevector(w23, w23, 2, 3), a3);
        }
        pr2[k][0] = a0; pr2[k][1] = a1; pr2[k][2] = a2; pr2[k][3] = a3;
        ks2[0] += a0; ks2[1] += a1; ks2[2] += a2; ks2[3] += a3;
    }

    // ---- dynamic routing, ITERS = 3 (normalized probs — bounded) ----
    float logits[KK];
    #pragma unroll
    for (int k = 0; k < KK; ++k) logits[k] = 0.0f;

    v2f vv[4];
    #pragma unroll
    for (int it = 0; it < 3; ++it) {
        v2f s2[4];
        if (it == 0) {
            #pragma unroll
            for (int j = 0; j < 4; ++j) s2[j] = ks2[j] * (1.0f / 9.0f);
        } else {
            float e[KK];
            float sum = 0.0f;
            #pragma unroll
            for (int k = 0; k < KK; ++k) { e[k] = __expf(logits[k]); sum += e[k]; }
            const float inv = 1.0f / sum;
            #pragma unroll
            for (int j = 0; j < 4; ++j) s2[j] = v2f{0.f, 0.f};
            #pragma unroll
            for (int k = 0; k < KK; ++k) {
                const v2f ek = {e[k], e[k]};
                #pragma unroll
                for (int j = 0; j < 4; ++j) s2[j] = fma2(ek, pr2[k][j], s2[j]);
            }
            const v2f inv2 = {inv, inv};
            #pragma unroll
            for (int j = 0; j < 4; ++j) s2[j] *= inv2;
        }

        // g-group all-reduce via DPP (VALU-only, no LDS pipe)
        #pragma unroll
        for (int j = 0; j < 4; ++j) { DPP_XADD(s2[j].x, 0xB1); DPP_XADD(s2[j].y, 0xB1); }
        #pragma unroll
        for (int j = 0; j < 4; ++j) { DPP_XADD(s2[j].x, 0x4E); DPP_XADD(s2[j].y, 0x4E); }
        #pragma unroll
        for (int j = 0; j < 4; ++j) { DPP_XADD(s2[j].x, 0x141); DPP_XADD(s2[j].y, 0x141); }

        // squash: f = sqrt(n2)/(1+n2) via rsq+rcp — denominator >= 1, NaN-free
        v2f tq = s2[0] * s2[0];
        tq = fma2(s2[1], s2[1], tq);
        tq = fma2(s2[2], s2[2], tq);
        tq = fma2(s2[3], s2[3], tq);
        const float n2 = tq.x + tq.y;
        const float f = n2 * __builtin_amdgcn_rsqf(fmaxf(n2, 1e-30f))
                           * __builtin_amdgcn_rcpf(1.0f + n2);
        const v2f f2 = {f, f};
        #pragma unroll
        for (int j = 0; j < 4; ++j) vv[j] = f2 * s2[j];

        if (it != 2) {
            #pragma unroll
            for (int k = 0; k < KK; ++k) {
                v2f d2 = pr2[k][0] * vv[0];
                d2 = fma2(pr2[k][1], vv[1], d2);
                d2 = fma2(pr2[k][2], vv[2], d2);
                d2 = fma2(pr2[k][3], vv[3], d2);
                logits[k] += d2.x + d2.y;
            }
        }
    }

    // lane (w, g) writes output component m = g (static select chain)
    const float vs[8] = { vv[0].x, vv[0].y, vv[1].x, vv[1].y,
                          vv[2].x, vv[2].y, vv[3].x, vv[3].y };
    float outv = vs[0];
    #pragma unroll
    for (int m = 1; m < LOUT; ++m) if (g == m) outv = vs[m];
    out[(n * GOUT * LOUT + c * LOUT + g) * HW + h * WW + w] = outv;
}

extern "C" void kernel_launch(void* const* d_in, const int* in_sizes, int n_in,
                              void* d_out, int out_size, void* d_ws, size_t ws_size,
                              hipStream_t stream) {
    const float* x  = (const float*)d_in[0];
    const float* wt = (const float*)d_in[1];
    float* out = (float*)d_out;

    dim3 grid(NB * HH, GOUT);   // 224 x 8, 448 threads (one image row x one c)
    caps_fused_kernel<<<grid, dim3(THREADS), 0, stream>>>(x, wt, out);
}